// Round 2
// baseline (660.210 us; speedup 1.0000x reference)
//
#include <hip/hip_runtime.h>
#include <math.h>

#define WIN 11
#define PADW 5
#define TH  16               // output rows per block
#define NR  (TH + WIN - 1)   // 26 input rows per block
#define BW  256              // output columns per block
#define IMG 512
#define NB  32
#define PLANE (IMG * IMG)

struct GaussW { float w[WIN]; };

__device__ __forceinline__ int reflect_idx(int x) {
    x = x < 0 ? -x : x;
    return x > IMG - 1 ? 2 * (IMG - 1) - x : x;
}

__global__ __launch_bounds__(256, 4) void ssim_cols(
    const float* __restrict__ img1, const float* __restrict__ img2,
    float* __restrict__ partial, GaussW gw)
{
    __shared__ float2 buf[2][BW + WIN - 1];   // (g1,g2) interleaved, 266 slots

    const int tid = threadIdx.x;
    const int bx  = blockIdx.x;     // 0..1  (column strip)
    const int by  = blockIdx.y;     // 0..31 (row strip)
    const int n   = blockIdx.z;     // batch
    const int x0  = bx * BW;
    const int ry0 = by * TH;

    const float* b1 = img1 + (size_t)n * 3 * PLANE;
    const float* b2 = img2 + (size_t)n * 3 * PLANE;

    const int xm = x0 + tid;                       // my staging column (interior always)
    const bool isPad = tid < 2 * PADW;             // threads 0..9 also fill halo slots
    const int padSlot = (tid < PADW) ? tid : (BW + tid);          // 0..4 or 261..265
    const int padX = reflect_idx((tid < PADW) ? (x0 + tid - PADW)
                                              : (x0 + BW - PADW + tid)); // x0-5.. / x0+256..

    // vertical accumulators: 5 quantities x TH output rows, all static-indexed
    float a0[TH], a1[TH], a2[TH], a3[TH], a4[TH];
    #pragma unroll
    for (int o = 0; o < TH; ++o) { a0[o]=0.f; a1[o]=0.f; a2[o]=0.f; a3[o]=0.f; a4[o]=0.f; }

    // ---- prologue: stage input row 0 into buf[0]
    {
        const int y = reflect_idx(ry0 - PADW);
        const float* q1 = b1 + (size_t)y * IMG;
        const float* q2 = b2 + (size_t)y * IMG;
        float ga = 0.299f*q1[xm] + 0.587f*q1[PLANE+xm] + 0.114f*q1[2*PLANE+xm];
        float gb = 0.299f*q2[xm] + 0.587f*q2[PLANE+xm] + 0.114f*q2[2*PLANE+xm];
        buf[0][tid + PADW] = make_float2(ga, gb);
        if (isPad) {
            float pa = 0.299f*q1[padX] + 0.587f*q1[PLANE+padX] + 0.114f*q1[2*PLANE+padX];
            float pb = 0.299f*q2[padX] + 0.587f*q2[PLANE+padX] + 0.114f*q2[2*PLANE+padX];
            buf[0][padSlot] = make_float2(pa, pb);
        }
    }
    __syncthreads();

    #pragma unroll
    for (int r = 0; r < NR; ++r) {
        // ---- issue global loads for row r+1 early (latency hides under window compute)
        float A0=0,A1v=0,A2=0,B0=0,B1v=0,B2=0;
        float P0=0,P1=0,P2=0,P3=0,P4=0,P5=0;
        if (r + 1 < NR) {
            const int y = reflect_idx(ry0 - PADW + r + 1);
            const float* q1 = b1 + (size_t)y * IMG;
            const float* q2 = b2 + (size_t)y * IMG;
            A0 = q1[xm]; A1v = q1[PLANE+xm]; A2 = q1[2*PLANE+xm];
            B0 = q2[xm]; B1v = q2[PLANE+xm]; B2 = q2[2*PLANE+xm];
            if (isPad) {
                P0 = q1[padX]; P1 = q1[PLANE+padX]; P2 = q1[2*PLANE+padX];
                P3 = q2[padX]; P4 = q2[PLANE+padX]; P5 = q2[2*PLANE+padX];
            }
        }

        // ---- horizontal 11-tap window on current row (ds_read_b64, 2-way = free)
        const float2* rowb = buf[r & 1];
        float h0=0.f, h1=0.f, h2=0.f, h3=0.f, h4=0.f;
        #pragma unroll
        for (int j = 0; j < WIN; ++j) {
            float2 ab = rowb[tid + j];
            float w = gw.w[j];
            h0 = fmaf(w, ab.x, h0);
            h1 = fmaf(w, ab.y, h1);
            h2 = fmaf(w, ab.x * ab.x, h2);
            h3 = fmaf(w, ab.y * ab.y, h3);
            h4 = fmaf(w, ab.x * ab.y, h4);
        }

        // ---- vertical accumulation into the <=11 output rows this input row feeds
        #pragma unroll
        for (int o = 0; o < TH; ++o) {
            const int t = r - o;                 // compile-time after unroll
            if (t >= 0 && t < WIN) {
                const float wt = gw.w[t];
                a0[o] = fmaf(wt, h0, a0[o]);
                a1[o] = fmaf(wt, h1, a1[o]);
                a2[o] = fmaf(wt, h2, a2[o]);
                a3[o] = fmaf(wt, h3, a3[o]);
                a4[o] = fmaf(wt, h4, a4[o]);
            }
        }

        // ---- gray-convert + LDS write of row r+1, then barrier
        if (r + 1 < NR) {
            float ga = 0.299f*A0 + 0.587f*A1v + 0.114f*A2;
            float gb = 0.299f*B0 + 0.587f*B1v + 0.114f*B2;
            buf[(r + 1) & 1][tid + PADW] = make_float2(ga, gb);
            if (isPad) {
                float pa = 0.299f*P0 + 0.587f*P1 + 0.114f*P2;
                float pb = 0.299f*P3 + 0.587f*P4 + 0.114f*P5;
                buf[(r + 1) & 1][padSlot] = make_float2(pa, pb);
            }
            __syncthreads();
        }
    }

    // ---- SSIM + interior mask + reduction
    const float C1 = 1e-4f, C2 = 9e-4f;
    const float COVN = 121.0f / 120.0f;
    float lsum = 0.0f;
    const int gx = x0 + tid;
    if (gx >= PADW && gx < IMG - PADW) {
        #pragma unroll
        for (int o = 0; o < TH; ++o) {
            const int gy = ry0 + o;
            if (gy >= PADW && gy < IMG - PADW) {
                float ux = a0[o], uy = a1[o];
                float vx  = COVN * (a2[o] - ux * ux);
                float vy  = COVN * (a3[o] - uy * uy);
                float vxy = COVN * (a4[o] - ux * uy);
                float A1s = 2.0f * ux * uy + C1;
                float A2s = 2.0f * vxy + C2;
                float B1s = ux * ux + uy * uy + C1;
                float B2s = vx + vy + C2;
                lsum += (A1s * A2s) / (B1s * B2s);
            }
        }
    }

    for (int off = 32; off > 0; off >>= 1)
        lsum += __shfl_down(lsum, off, 64);
    __shared__ float wsum[4];
    const int wid = tid >> 6, lane = tid & 63;
    if (lane == 0) wsum[wid] = lsum;
    __syncthreads();
    if (tid == 0) {
        partial[((size_t)n * gridDim.y + by) * gridDim.x + bx] =
            wsum[0] + wsum[1] + wsum[2] + wsum[3];
    }
}

__global__ __launch_bounds__(256) void ssim_reduce(
    const float* __restrict__ partial, float* __restrict__ out,
    int nblocks, double inv_count)
{
    __shared__ double sm[256];
    double s = 0.0;
    for (int i = threadIdx.x; i < nblocks; i += 256) s += (double)partial[i];
    sm[threadIdx.x] = s;
    __syncthreads();
    for (int off = 128; off > 0; off >>= 1) {
        if (threadIdx.x < off) sm[threadIdx.x] += sm[threadIdx.x + off];
        __syncthreads();
    }
    if (threadIdx.x == 0) out[0] = (float)(sm[0] * inv_count);
}

extern "C" void kernel_launch(void* const* d_in, const int* in_sizes, int n_in,
                              void* d_out, int out_size, void* d_ws, size_t ws_size,
                              hipStream_t stream) {
    const float* img1 = (const float*)d_in[0];
    const float* img2 = (const float*)d_in[1];
    float* out = (float*)d_out;
    float* partial = (float*)d_ws;

    GaussW gw;
    {
        double e[WIN], s = 0.0;
        for (int i = 0; i < WIN; ++i) {
            double d = (double)(i - PADW);
            e[i] = exp(-(d * d) / (2.0 * 1.5 * 1.5));
            s += e[i];
        }
        for (int i = 0; i < WIN; ++i) gw.w[i] = (float)(e[i] / s);
    }

    dim3 grid(IMG / BW, IMG / TH, NB);   // (2, 32, 32) = 2048 blocks
    ssim_cols<<<grid, 256, 0, stream>>>(img1, img2, partial, gw);

    const int nblocks = (IMG / BW) * (IMG / TH) * NB;   // 2048
    const double inv_count = 1.0 / (double)((size_t)NB * (IMG - 2 * PADW) * (IMG - 2 * PADW));
    ssim_reduce<<<1, 256, 0, stream>>>(partial, out, nblocks, inv_count);
}